// Round 1
// baseline (376.790 us; speedup 1.0000x reference)
//
#include <hip/hip_runtime.h>
#include <hip/hip_bf16.h>

constexpr int Sdim = 256;
constexpr int Cdim = 128;
constexpr int CRdim = 32;
constexpr int Bdim = 2;
constexpr int SS = Sdim * Sdim;      // 65536
constexpr int NPOS = Bdim * SS;      // 131072

__device__ __forceinline__ float bf2f(unsigned short v) {
    union { unsigned u; float f; } t; t.u = ((unsigned)v) << 16; return t.f;
}
__device__ __forceinline__ unsigned short f2bf(float f) {
    unsigned u = __float_as_uint(f);
    return (unsigned short)((u + 0x7fffu + ((u >> 16) & 1u)) >> 16);
}

// ---------------- K0: weight prep ----------------
// wred_t[c][cr] = w_reduce[cr][c]  (so pointwise kernel s_loads 32 contiguous f32)
// wA[c][co] = w_merge[co][c] + w_merge[co][128+c]
// wB[c][co] = w_merge[co][256+c] + w_merge[co][384+c]
__global__ void k_prep(const float* __restrict__ w_reduce,
                       const float* __restrict__ w_merge,
                       float* __restrict__ wred_t,
                       float* __restrict__ wA, float* __restrict__ wB) {
    int t = blockIdx.x * 256 + threadIdx.x;   // 0..16383
    if (t < Cdim * CRdim) {
        int c = t >> 5, cr = t & 31;
        wred_t[c * CRdim + cr] = w_reduce[cr * Cdim + c];
    }
    int c = t >> 7, co = t & 127;
    wA[t] = w_merge[co * 512 + c]       + w_merge[co * 512 + 128 + c];
    wB[t] = w_merge[co * 512 + 256 + c] + w_merge[co * 512 + 384 + c];
}

// ---------------- K1: fused pointwise (red -> u, lam, gains) ----------------
__global__ __launch_bounds__(256) void k_pointwise(
    const float* __restrict__ x,
    const float* __restrict__ wred_t, const float* __restrict__ b_red,
    const float* __restrict__ w_u,    const float* __restrict__ b_u,
    const float* __restrict__ w_lam,  const float* __restrict__ b_lam,
    const float* __restrict__ w_w,    const float* __restrict__ b_w,
    unsigned short* __restrict__ u_o, unsigned short* __restrict__ lam_o,
    float* __restrict__ Gv, float* __restrict__ Gh)
{
    int p  = blockIdx.x * 256 + threadIdx.x;   // b*SS + hw
    int b  = p >> 16;
    int hw = p & (SS - 1);
    int h  = hw >> 8, w = hw & 255;

    float red[CRdim];
    #pragma unroll
    for (int cr = 0; cr < CRdim; ++cr) red[cr] = b_red[cr];

    const float* xp = x + (size_t)b * Cdim * SS + hw;
    #pragma unroll 2
    for (int c = 0; c < Cdim; ++c) {
        float xv = xp[(size_t)c * SS];
        const float* wr = wred_t + c * CRdim;     // uniform -> s_load
        #pragma unroll
        for (int cr = 0; cr < CRdim; ++cr) red[cr] = fmaf(wr[cr], xv, red[cr]);
    }

    unsigned short* up = u_o   + (size_t)b * Cdim * SS + hw;
    unsigned short* lp = lam_o + (size_t)b * Cdim * SS + hw;
    #pragma unroll 2
    for (int c = 0; c < Cdim; ++c) {
        float au = b_u[c], al = b_lam[c];
        const float* wu = w_u   + c * CRdim;
        const float* wl = w_lam + c * CRdim;
        #pragma unroll
        for (int cr = 0; cr < CRdim; ++cr) {
            au = fmaf(wu[cr], red[cr], au);
            al = fmaf(wl[cr], red[cr], al);
        }
        up[(size_t)c * SS] = f2bf(au);
        lp[(size_t)c * SS] = f2bf(al);
    }

    float pre[3];
    #pragma unroll
    for (int k = 0; k < 3; ++k) {
        float a = b_w[k];
        const float* ww = w_w + k * CRdim;
        #pragma unroll
        for (int cr = 0; cr < CRdim; ++cr) a = fmaf(ww[cr], red[cr], a);
        pre[k] = a;
    }
    float s0 = 1.f / (1.f + expf(-pre[0]));
    float s1 = 1.f / (1.f + expf(-pre[1]));
    float s2 = 1.f / (1.f + expf(-pre[2]));
    float inv = 1.f / fmaxf(s0 + s1 + s2, 1e-6f);
    // Gh[b,i=h,j=w]: gain for horizontal scan (wsn at (h,w), masks at h)
    float gh = (s1 + (h >= 1 ? s0 : 0.f) + (h <= Sdim - 2 ? s2 : 0.f)) * inv;
    // Gv[b,i=w,j=h]: gain for vertical scan (wsn at (j,i) transposed access, masks at i=w)
    float gv = (s1 + (w >= 1 ? s0 : 0.f) + (w <= Sdim - 2 ? s2 : 0.f)) * inv;
    Gh[(b << 16) + hw] = gh;
    Gv[(b << 16) + (w << 8) + h] = gv;
}

// ---------------- K2: both scans in one launch (512 blocks) ----------------
__global__ __launch_bounds__(256) void k_scan_both(
    const float* __restrict__ x,
    const unsigned short* __restrict__ u, const unsigned short* __restrict__ lam,
    const float* __restrict__ Gv, const float* __restrict__ Gh,
    unsigned short* __restrict__ ov, unsigned short* __restrict__ oh)
{
    int id = blockIdx.x;
    int j  = threadIdx.x;
    if (id < Bdim * Cdim) {
        // vertical: o_v[b,c,i,j] = h_i * u[b,c,i,j]; h = h*Gv[b,i,j] + lam*x at (i,j)
        int bc = id, b = bc >> 7;
        size_t base = (size_t)bc * SS + j;
        const float* Gb = Gv + (b << 16) + j;
        float h = 0.f;
        #pragma unroll 8
        for (int i = 0; i < Sdim; ++i) {
            size_t idx = base + ((size_t)i << 8);
            float g = Gb[i << 8];
            h = fmaf(h, g, bf2f(lam[idx]) * x[idx]);
            ov[idx] = f2bf(h * bf2f(u[idx]));
        }
    } else {
        // horizontal (output kept in transposed coords, matching reference concat):
        // o_h[b,c,i,j] = h_i * u[b,c,j,i]; h = h*Gh[b,i,j] + lam[b,c,j,i]*x[b,c,j,i]
        int bc = id - Bdim * Cdim, b = bc >> 7;
        size_t rbase = (size_t)bc * SS + (size_t)j * Sdim;  // + i   (row stream)
        size_t obase = (size_t)bc * SS + j;                 // + (i<<8)
        const float* Gb = Gh + (b << 16) + j;
        float h = 0.f;
        for (int i0 = 0; i0 < Sdim; i0 += 4) {
            float4  xv = *reinterpret_cast<const float4*>(x + rbase + i0);
            ushort4 uv = *reinterpret_cast<const ushort4*>(u + rbase + i0);
            ushort4 lv = *reinterpret_cast<const ushort4*>(lam + rbase + i0);
            float xk[4] = {xv.x, xv.y, xv.z, xv.w};
            unsigned short uu[4] = {uv.x, uv.y, uv.z, uv.w};
            unsigned short ll[4] = {lv.x, lv.y, lv.z, lv.w};
            #pragma unroll
            for (int k = 0; k < 4; ++k) {
                float g = Gb[(i0 + k) << 8];
                h = fmaf(h, g, bf2f(ll[k]) * xk[k]);
                oh[obase + ((size_t)(i0 + k) << 8)] = f2bf(h * bf2f(uu[k]));
            }
        }
    }
}

// ---------------- K3: merge (channel GEMM, VALU f32) ----------------
__global__ __launch_bounds__(256, 2) void k_merge(
    const unsigned short* __restrict__ ov, const unsigned short* __restrict__ oh,
    const float* __restrict__ wA, const float* __restrict__ wB,
    const float* __restrict__ b_merge, float* __restrict__ out)
{
    int p  = blockIdx.x * 256 + threadIdx.x;   // b*SS + ij
    int b  = p >> 16;
    int ij = p & (SS - 1);

    float acc[Cdim];
    #pragma unroll
    for (int co = 0; co < Cdim; ++co) acc[co] = b_merge[co];

    const unsigned short* ovp = ov + (size_t)b * Cdim * SS + ij;
    const unsigned short* ohp = oh + (size_t)b * Cdim * SS + ij;
    for (int c = 0; c < Cdim; ++c) {
        float v = bf2f(ovp[(size_t)c << 16]);
        const float* wp = wA + c * Cdim;      // uniform -> s_load
        #pragma unroll
        for (int co = 0; co < Cdim; ++co) acc[co] = fmaf(wp[co], v, acc[co]);
    }
    for (int c = 0; c < Cdim; ++c) {
        float v = bf2f(ohp[(size_t)c << 16]);
        const float* wp = wB + c * Cdim;
        #pragma unroll
        for (int co = 0; co < Cdim; ++co) acc[co] = fmaf(wp[co], v, acc[co]);
    }
    float* op = out + (size_t)b * Cdim * SS + ij;
    #pragma unroll
    for (int co = 0; co < Cdim; ++co) op[(size_t)co << 16] = acc[co];
}

extern "C" void kernel_launch(void* const* d_in, const int* in_sizes, int n_in,
                              void* d_out, int out_size, void* d_ws, size_t ws_size,
                              hipStream_t stream)
{
    const float* x        = (const float*)d_in[0];
    const float* w_reduce = (const float*)d_in[1];
    const float* b_red    = (const float*)d_in[2];
    const float* w_u      = (const float*)d_in[3];
    const float* b_u      = (const float*)d_in[4];
    const float* w_lam    = (const float*)d_in[5];
    const float* b_lam    = (const float*)d_in[6];
    const float* w_w      = (const float*)d_in[7];
    const float* b_w      = (const float*)d_in[8];
    const float* w_merge  = (const float*)d_in[11];
    const float* b_merge  = (const float*)d_in[12];
    float* out = (float*)d_out;

    char* ws = (char*)d_ws;
    unsigned short* u_buf   = (unsigned short*)(ws);                 // 32 MiB bf16
    unsigned short* lam_buf = (unsigned short*)(ws + 33554432);      // 32 MiB
    unsigned short* ov      = (unsigned short*)(ws + 67108864);      // 32 MiB
    unsigned short* oh      = (unsigned short*)(ws + 100663296);     // 32 MiB
    float* Gv    = (float*)(ws + 134217728);                         // 512 KiB
    float* Gh    = (float*)(ws + 134742016);                         // 512 KiB
    float* wredt = (float*)(ws + 135266304);                         // 16 KiB
    float* wA    = (float*)(ws + 135282688);                         // 64 KiB
    float* wB    = (float*)(ws + 135348224);                         // 64 KiB

    hipLaunchKernelGGL(k_prep, dim3(64), dim3(256), 0, stream,
                       w_reduce, w_merge, wredt, wA, wB);
    hipLaunchKernelGGL(k_pointwise, dim3(NPOS / 256), dim3(256), 0, stream,
                       x, wredt, b_red, w_u, b_u, w_lam, b_lam, w_w, b_w,
                       u_buf, lam_buf, Gv, Gh);
    hipLaunchKernelGGL(k_scan_both, dim3(2 * Bdim * Cdim), dim3(256), 0, stream,
                       x, u_buf, lam_buf, Gv, Gh, ov, oh);
    hipLaunchKernelGGL(k_merge, dim3(NPOS / 256), dim3(256), 0, stream,
                       ov, oh, wA, wB, b_merge, out);
}